// Round 1
// baseline (510.285 us; speedup 1.0000x reference)
//
#include <hip/hip_runtime.h>
#include <math.h>

// Problem constants
#define BB   32
#define DD   512
#define NN   512
#define CC   512
#define HW   4096           // 64*64
#define NLOC (BB * HW)      // 131072 locations
#define NBD  (BB * DD)      // 16384 q outputs
#define NBC  (BB * CC)      // 16384 ct outputs

__device__ __forceinline__ float wave_reduce_sum(float v) {
#pragma unroll
    for (int m = 1; m < 64; m <<= 1) v += __shfl_xor(v, m, 64);
    return v;
}

__device__ __forceinline__ float wave_reduce_max(float v) {
#pragma unroll
    for (int m = 1; m < 64; m <<= 1) v = fmaxf(v, __shfl_xor(v, m, 64));
    return v;
}

// Stable, branch-free tanh: 1 - 2/(e^{2x}+1).
// x -> +inf: e^{2x}=inf -> 1; x -> -inf: e^{2x}=0 -> -1. No NaN anywhere.
__device__ __forceinline__ float tanh_fast(float x) {
    float t = __expf(2.0f * x);
    return 1.0f - 2.0f * __builtin_amdgcn_rcpf(t + 1.0f);
}

// ---------------- Kernel 1: q = ht_query @ Wq^T  ([B,N]@[N,D] -> [B,D]) ----
// One wave per output element. grid = NBD/4 blocks of 256 threads.
__global__ void qproj_kernel(const float* __restrict__ hq,
                             const float* __restrict__ Wq,
                             float* __restrict__ q) {
    int wid  = threadIdx.x >> 6;
    int lane = threadIdx.x & 63;
    int idx  = blockIdx.x * 4 + wid;       // 0 .. NBD-1
    int b = idx >> 9;                      // /512
    int d = idx & 511;
    const float* hrow = hq + (size_t)b * NN;
    const float* wrow = Wq + (size_t)d * NN;
    float acc = 0.0f;
#pragma unroll
    for (int j = 0; j < 2; ++j) {
        int n = j * 256 + lane * 4;
        float4 h = *(const float4*)(hrow + n);
        float4 w = *(const float4*)(wrow + n);
        acc += h.x * w.x + h.y * w.y + h.z * w.z + h.w * w.w;
    }
    acc = wave_reduce_sum(acc);
    if (lane == 0) q[idx] = acc;
}

// ---------------- Kernel 2: raw scores + per-block max ---------------------
// s_raw[b,h,w] = sum_d Wa[d]*tanh(key[b,h,w,d] + q[b,d]) + ba
// One wave per location. grid = NLOC/4 blocks of 256 threads.
__global__ void score_kernel(const float* __restrict__ key,
                             const float* __restrict__ q,
                             const float* __restrict__ Wa,
                             const float* __restrict__ ba,
                             float* __restrict__ s_raw,
                             float* __restrict__ blkmax) {
    __shared__ float smax[4];
    int wid  = threadIdx.x >> 6;
    int lane = threadIdx.x & 63;
    int idx  = blockIdx.x * 4 + wid;       // 0 .. NLOC-1
    int b = idx >> 12;                     // /4096
    const float* krow = key + (size_t)idx * DD;
    const float* qrow = q + (size_t)b * DD;
    float acc = 0.0f;
#pragma unroll
    for (int j = 0; j < 2; ++j) {
        int n = j * 256 + lane * 4;
        float4 k = *(const float4*)(krow + n);
        float4 qq = *(const float4*)(qrow + n);
        float4 w = *(const float4*)(Wa + n);
        acc += w.x * tanh_fast(k.x + qq.x);
        acc += w.y * tanh_fast(k.y + qq.y);
        acc += w.z * tanh_fast(k.z + qq.z);
        acc += w.w * tanh_fast(k.w + qq.w);
    }
    acc = wave_reduce_sum(acc);
    float s = acc + ba[0];
    if (lane == 0) { s_raw[idx] = s; smax[wid] = s; }
    __syncthreads();
    if (threadIdx.x == 0) {
        blkmax[blockIdx.x] = fmaxf(fmaxf(smax[0], smax[1]), fmaxf(smax[2], smax[3]));
    }
}

// ---------------- Kernel 3: global max over block maxima -------------------
// Single block, 1024 threads.
__global__ void maxred_kernel(const float* __restrict__ blkmax, int n,
                              float* __restrict__ gmax) {
    __shared__ float sm[16];
    float m = -INFINITY;
    for (int i = threadIdx.x; i < n; i += 1024) m = fmaxf(m, blkmax[i]);
    m = wave_reduce_max(m);
    int wid = threadIdx.x >> 6, lane = threadIdx.x & 63;
    if (lane == 0) sm[wid] = m;
    __syncthreads();
    if (threadIdx.x == 0) {
        float g = sm[0];
#pragma unroll
        for (int i = 1; i < 16; ++i) g = fmaxf(g, sm[i]);
        gmax[0] = g;
    }
}

// ---------------- Kernel 4: per-batch softmax ------------------------------
// s_out[b,hw] = exp(s_raw - gmax)*mask / (sum_hw(...) + 1e-10)
// One block (256 threads) per batch; 16 elements per thread.
__global__ void softmax_kernel(const float* __restrict__ s_raw,
                               const float* __restrict__ mask,
                               const float* __restrict__ gmax,
                               float* __restrict__ s_out) {
    __shared__ float sm[4];
    int b = blockIdx.x;
    float gm = gmax[0];
    size_t base = (size_t)b * HW;
    float e[16];
    float psum = 0.0f;
#pragma unroll
    for (int j = 0; j < 16; ++j) {
        int i = j * 256 + threadIdx.x;
        float v = __expf(s_raw[base + i] - gm) * mask[base + i];
        e[j] = v;
        psum += v;
    }
    psum = wave_reduce_sum(psum);
    int wid = threadIdx.x >> 6, lane = threadIdx.x & 63;
    if (lane == 0) sm[wid] = psum;
    __syncthreads();
    float total = sm[0] + sm[1] + sm[2] + sm[3];
    float inv = 1.0f / (total + 1e-10f);
#pragma unroll
    for (int j = 0; j < 16; ++j) {
        int i = j * 256 + threadIdx.x;
        s_out[base + i] = e[j] * inv;
    }
}

// ---------------- Kernel 5: ct[b,c] = dot(ctx_val[b,c,:], s[b,:]) ----------
// One wave per (b,c). grid = NBC/4 blocks of 256 threads.
__global__ void ct_kernel(const float* __restrict__ val,
                          const float* __restrict__ s,
                          float* __restrict__ ct) {
    int wid  = threadIdx.x >> 6;
    int lane = threadIdx.x & 63;
    int idx  = blockIdx.x * 4 + wid;       // 0 .. NBC-1 ; idx = b*512 + c
    int b = idx >> 9;
    const float* vrow = val + (size_t)idx * HW;   // [B,C,HW] contiguous
    const float* srow = s + (size_t)b * HW;
    float acc = 0.0f;
#pragma unroll
    for (int j = 0; j < 16; ++j) {
        int h = j * 256 + lane * 4;
        float4 v = *(const float4*)(vrow + h);
        float4 w = *(const float4*)(srow + h);
        acc += v.x * w.x + v.y * w.y + v.z * w.z + v.w * w.w;
    }
    acc = wave_reduce_sum(acc);
    if (lane == 0) ct[idx] = acc;
}

extern "C" void kernel_launch(void* const* d_in, const int* in_sizes, int n_in,
                              void* d_out, int out_size, void* d_ws, size_t ws_size,
                              hipStream_t stream) {
    const float* ctx_val  = (const float*)d_in[0];   // [B,C,H,W]
    const float* ctx_key  = (const float*)d_in[1];   // [B,H,W,D]
    const float* ctx_mask = (const float*)d_in[2];   // [B,H,W]
    const float* ht_query = (const float*)d_in[3];   // [B,N]
    const float* Wq       = (const float*)d_in[4];   // [D,N]
    const float* Wa       = (const float*)d_in[5];   // [1,D]
    const float* ba       = (const float*)d_in[6];   // [1]

    float* ct_out = (float*)d_out;                   // [B,C] = 16384
    float* s_out  = (float*)d_out + NBC;             // [B,H,W] = 131072

    float* ws     = (float*)d_ws;
    float* q      = ws;                              // 16384
    float* s_raw  = ws + NBD;                        // 131072
    float* blkmax = ws + NBD + NLOC;                 // 32768
    float* gmax   = ws + NBD + NLOC + NLOC / 4;      // 1

    const int SCORE_BLOCKS = NLOC / 4;               // 32768

    qproj_kernel<<<NBD / 4, 256, 0, stream>>>(ht_query, Wq, q);
    score_kernel<<<SCORE_BLOCKS, 256, 0, stream>>>(ctx_key, q, Wa, ba, s_raw, blkmax);
    maxred_kernel<<<1, 1024, 0, stream>>>(blkmax, SCORE_BLOCKS, gmax);
    softmax_kernel<<<BB, 256, 0, stream>>>(s_raw, ctx_mask, gmax, s_out);
    ct_kernel<<<NBC / 4, 256, 0, stream>>>(ctx_val, s_out, ct_out);
}